// Round 11
// baseline (183.656 us; speedup 1.0000x reference)
//
#include <hip/hip_runtime.h>
#include <math.h>

typedef __attribute__((ext_vector_type(8))) short short8;
typedef __attribute__((ext_vector_type(4))) float f32x4;
typedef __attribute__((ext_vector_type(2))) float f32x2;

#define TX 16
#define TY 8
#define IH 256
#define IW 256

// ws byte layout: [0,16384) kc f32[64][64]; [16384,81920) wsA frags ushort;
//                 [81920,114688) wsC frags ushort
#define WSA_OFF 16384
#define WSC_OFF 81920

// LDS layout (bytes):
//   H: [16 ch-pair planes][816] = 10 rows x 80B (18 px x 4B f16-pair + pad)
//   G: @13056: [128 px][64B = 4 granules of 16B, XOR gi = (ch>>3)^(px>>4 & 3)]
//   slow-path YS f32[32][132] (16896 B) overlays @0
#define H_STRIDE 816
#define G_OFF 13056
#define SMEM_BYTES 29440

#define SP2(c) ((f32x2){(c), (c)})

__device__ __forceinline__ unsigned short f2bf(float f) {
  unsigned int u = __builtin_bit_cast(unsigned int, f);
  u = (u + 0x7FFFu + ((u >> 16) & 1u)) >> 16;
  return (unsigned short)u;
}

__global__ void edffn_prep(const float* __restrict__ fftf,
                           const float* __restrict__ w_in,
                           const float* __restrict__ w_out,
                           float* __restrict__ ws) {
  int blk = blockIdx.x, t = threadIdx.x;
  if (blk < 64) {
    // kc = irfft2 of the (real, symmetric) full-spectrum multiplier
    int a = t >> 3, bb = t & 7;
    const float c0 = 0.70710678118654752f;
    const float ctab[8] = {1.f, c0, 0.f, -c0, -1.f, -c0, 0.f, c0};
    const float* F = fftf + blk * 40;  // [8][5]
    float acc = 0.f;
    for (int k1 = 0; k1 < 8; ++k1)
      for (int k2 = 0; k2 < 8; ++k2) {
        float f = (k2 <= 4) ? F[k1 * 5 + k2] : F[((8 - k1) & 7) * 5 + (8 - k2)];
        acc += f * ctab[(k1 * a + k2 * bb) & 7];
      }
    ws[blk * 64 + t] = acc * (1.f / 64.f);
  } else if (blk < 128) {
    // w_in A-fragments: [chunk q=0..15][s=0,1][ks=0,1][lane][8]
    int b2 = blk - 64;
    int q = b2 >> 2, s = (b2 >> 1) & 1, ks = b2 & 1;
    int row = (s ? 256 : 0) + q * 16 + (t & 15);
    unsigned short* dst =
        (unsigned short*)((unsigned char*)ws + WSA_OFF) + (((q * 2 + s) * 2 + ks) * 64 + t) * 8;
    for (int j = 0; j < 8; ++j) {
      int k = ks * 32 + (t >> 4) * 8 + j;
      dst[j] = f2bf(w_in[row * 64 + k]);
    }
  } else {
    // w_out A-fragments: [pair p=0..7][mtile=0..3][lane][8]
    int b3 = blk - 128;
    int p = b3 >> 2, mt = b3 & 3;
    int row = mt * 16 + (t & 15);
    unsigned short* dst =
        (unsigned short*)((unsigned char*)ws + WSC_OFF) + ((p * 4 + mt) * 64 + t) * 8;
    for (int j = 0; j < 8; ++j) {
      int k = p * 32 + (t >> 4) * 8 + j;
      dst[j] = f2bf(w_out[row * 256 + k]);
    }
  }
}

__global__ __launch_bounds__(256, 2) void edffn_main(
    const float* __restrict__ x, const float* __restrict__ b_in,
    const float* __restrict__ w_dw, const float* __restrict__ b_dw,
    const float* __restrict__ b_out, const float* __restrict__ ws,
    float* __restrict__ out) {
  __shared__ __align__(16) unsigned char smem[SMEM_BYTES];
  __shared__ int s_flag;
  const int t = threadIdx.x;
  const int lane = t & 63, wave = t >> 6;
  const int l15 = lane & 15, lg = lane >> 4;
  const int gx0 = blockIdx.x * TX, gy0 = blockIdx.y * TY;
  const int b = blockIdx.z;
  const unsigned short* wsA = (const unsigned short*)((const unsigned char*)ws + WSA_OFF);
  const unsigned short* wsC = (const unsigned short*)((const unsigned char*)ws + WSC_OFF);

  // ---- stage-A B-fragments (x halo, bf16) in registers; halo = 10x18 = 180 px ----
  short8 xf[3][2];
  int haddr[3];
  unsigned vmask = 0, imask = 0;
  const float* xb = x + (size_t)b * 64 * 65536;
#pragma unroll
  for (int i = 0; i < 3; ++i) {
    int nt = wave + 4 * i;  // 12 tiles, 3 per wave
    int n = nt * 16 + l15;  // 0..191; valid < 180
    int hy = n / 18;
    int hx = n - hy * 18;
    int gy = gy0 + hy - 1, gx = gx0 + hx - 1;
    int vnt = n < 180;
    int inb = vnt & (gy >= 0) & (gy < IH) & (gx >= 0) & (gx < IW);
    haddr[i] = hy * 80 + hx * 4;
    vmask |= (unsigned)vnt << i;
    imask |= (unsigned)inb << i;
    int gyc = min(max(gy, 0), IH - 1), gxc = min(max(gx, 0), IW - 1);
    const float* xp = xb + (size_t)gyc * IW + gxc;
#pragma unroll
    for (int ks = 0; ks < 2; ++ks) {
#pragma unroll
      for (int j = 0; j < 8; ++j) {
        int k = ks * 32 + lg * 8 + j;
        unsigned short bf = f2bf(xp[(size_t)k * 65536]);
        xf[i][ks][j] = (short)(inb ? bf : (unsigned short)0);
      }
    }
  }

  f32x4 accY[8];
#pragma unroll
  for (int i = 0; i < 8; ++i) accY[i] = (f32x4){0.f, 0.f, 0.f, 0.f};

  const int cp_dw = t >> 4;         // channel-in-chunk
  const int oy_dw = (t & 15) >> 1;  // 0..7 output row
  const int h_dw = t & 1;           // ox half

  short8 afN[2][2];
  float binN[2][4];
  unsigned wdC[9], wdN[9], bdC, bdN;
  short8 cfC;
  unsigned ha[3][4];  // packed f16 (h1,h2) H values for the chunk in flight

  auto loadAF = [&](int qq) {
#pragma unroll
    for (int s = 0; s < 2; ++s) {
#pragma unroll
      for (int ks = 0; ks < 2; ++ks)
        afN[s][ks] = *(const short8*)(wsA + (((qq * 2 + s) * 2 + ks) * 64 + lane) * 8);
#pragma unroll
      for (int r = 0; r < 4; ++r) binN[s][r] = b_in[(s ? 256 : 0) + qq * 16 + lg * 4 + r];
    }
  };
  auto loadWD = [&](int qq, unsigned (&wd)[9], unsigned& bd) {
    const int cg1 = qq * 16 + cp_dw, cg2 = 256 + qq * 16 + cp_dw;
#pragma unroll
    for (int u = 0; u < 9; ++u) {
      float w1 = w_dw[cg1 * 9 + u], w2 = w_dw[cg2 * 9 + u];
      asm("v_cvt_pkrtz_f16_f32 %0, %1, %2" : "=v"(wd[u]) : "v"(w1), "v"(w2));
    }
    float b1 = b_dw[cg1], b2 = b_dw[cg2];
    asm("v_cvt_pkrtz_f16_f32 %0, %1, %2" : "=v"(bd) : "v"(b1), "v"(b2));
  };
  // MFMA for chunk whose af/bin are in afN/binN -> packed f16 pairs in ha
  auto computeA = [&]() {
#pragma unroll
    for (int i = 0; i < 3; ++i) {
      f32x4 acc0 = {0.f, 0.f, 0.f, 0.f}, acc1 = {0.f, 0.f, 0.f, 0.f};
      acc0 = __builtin_amdgcn_mfma_f32_16x16x32_bf16(afN[0][0], xf[i][0], acc0, 0, 0, 0);
      acc0 = __builtin_amdgcn_mfma_f32_16x16x32_bf16(afN[0][1], xf[i][1], acc0, 0, 0, 0);
      acc1 = __builtin_amdgcn_mfma_f32_16x16x32_bf16(afN[1][0], xf[i][0], acc1, 0, 0, 0);
      acc1 = __builtin_amdgcn_mfma_f32_16x16x32_bf16(afN[1][1], xf[i][1], acc1, 0, 0, 0);
      unsigned keep = (imask >> i) & 1u;
#pragma unroll
      for (int r = 0; r < 4; ++r) {
        float v0 = acc0[r] + binN[0][r];
        float v1 = acc1[r] + binN[1][r];
        unsigned pk;
        asm("v_cvt_pkrtz_f16_f32 %0, %1, %2" : "=v"(pk) : "v"(v0), "v"(v1));
        ha[i][r] = keep ? pk : 0u;  // SAME pad: h=0 outside image
      }
    }
  };

  // ---- prologue ----
  loadAF(0);
  loadWD(0, wdC, bdC);
  cfC = *(const short8*)(wsC + ((0 * 4 + wave) * 64 + lane) * 8);
  computeA();  // chunk 0 -> ha

  for (int q = 0; q < 16; ++q) {
    // ---- store H(q) from registers (b32, 1-beat stores) ----
#pragma unroll
    for (int i = 0; i < 3; ++i) {
      if ((vmask >> i) & 1u) {
#pragma unroll
        for (int r = 0; r < 4; ++r)
          *(unsigned*)(smem + (lg * 4 + r) * H_STRIDE + haddr[i]) = ha[i][r];
      }
    }
    // issue next chunk's weight loads (covered by barrier + dwconv)
    if (q < 15) {
      loadAF(q + 1);
      loadWD(q + 1, wdN, bdN);
    }
    __syncthreads();

    // ---- stage A for q+1 into registers: MFMA overlaps dwconv's VALU below ----
    if (q < 15) computeA();

    // ---- dwconv 3x3 + exact GELU gate (thread = (cp, oy, h-half); pk f16 math) ----
    {
      const int cp = cp_dw, oy = oy_dw, h = h_dw;
      unsigned a[8];
#pragma unroll
      for (int j = 0; j < 8; ++j) a[j] = bdC;
#pragma unroll
      for (int dy = 0; dy < 3; ++dy) {
        const unsigned char* base = smem + cp * H_STRIDE + (oy + dy) * 80 + h * 32;
        uint4 r0 = *(const uint4*)base;
        uint4 r1 = *(const uint4*)(base + 16);
        uint2 r2 = *(const uint2*)(base + 32);
        unsigned e[10] = {r0.x, r0.y, r0.z, r0.w, r1.x, r1.y, r1.z, r1.w, r2.x, r2.y};
#pragma unroll
        for (int ox = 0; ox < 8; ++ox) {
#pragma unroll
          for (int dx = 0; dx < 3; ++dx)
            asm("v_pk_fma_f16 %0, %1, %2, %0"
                : "+v"(a[ox])
                : "v"(wdC[dy * 3 + dx]), "v"(e[ox + dx]));
        }
      }
      const int c2 = (q & 1) * 16 + cp;
      const int gi = (c2 >> 3) ^ (oy & 3);  // 16B-granule XOR swizzle (involution)
      unsigned short* Gp =
          (unsigned short*)(smem + G_OFF) + oy * 16 * 32 + gi * 8 + (c2 & 7);
      // unpack accumulators, exact GELU(a1)*a2 pk-paired across ox
#pragma unroll
      for (int j = 0; j < 4; ++j) {
        unsigned a0 = a[2 * j], a1 = a[2 * j + 1];
        unsigned a0h = a0 >> 16, a1h = a1 >> 16;
        f32x2 u, v;
        asm("v_cvt_f32_f16 %0, %1" : "=v"(u[0]) : "v"(a0));
        asm("v_cvt_f32_f16 %0, %1" : "=v"(u[1]) : "v"(a1));
        asm("v_cvt_f32_f16 %0, %1" : "=v"(v[0]) : "v"(a0h));
        asm("v_cvt_f32_f16 %0, %1" : "=v"(v[1]) : "v"(a1h));
        f32x2 z = u * 0.70710678118654752f;
        f32x2 z2 = z * z;
        f32x2 erfv;
        if (__builtin_expect(fmaxf(z2[0], z2[1]) > 0.16f, 0)) {
          erfv[0] = erff(z[0]);  // exact fallback (not taken for this data)
          erfv[1] = erff(z[1]);
        } else {  // 5-term odd Taylor, |err|<3e-8 on |z|<=0.4
          f32x2 p = __builtin_elementwise_fma(z2, SP2(1.f / 216.f), SP2(-1.f / 42.f));
          p = __builtin_elementwise_fma(z2, p, SP2(1.f / 10.f));
          p = __builtin_elementwise_fma(z2, p, SP2(-1.f / 3.f));
          p = __builtin_elementwise_fma(z2, p, SP2(1.f));
          erfv = 1.12837916709551257f * (z * p);
        }
        f32x2 tt = __builtin_elementwise_fma(erfv, SP2(0.5f), SP2(0.5f));  // (1+erf)/2
        f32x2 g = (u * tt) * v;
        Gp[(h * 8 + 2 * j) * 32] = f2bf(g[0]);
        Gp[(h * 8 + 2 * j + 1) * 32] = f2bf(g[1]);
      }
    }
    __syncthreads();

    // ---- stage C at odd q: y += w_out[:, pair p] @ G (32 ch written at q-1,q) ----
    if (q & 1) {
      const int p = q >> 1;
      const unsigned short* G = (const unsigned short*)(smem + G_OFF);
#pragma unroll
      for (int nt = 0; nt < 8; ++nt) {
        int g = lg ^ (nt & 3);  // reader-side XOR (nt uniform per instr)
        int n = nt * 16 + l15;
        short8 bf = *(const short8*)(G + n * 32 + g * 8);
        accY[nt] = __builtin_amdgcn_mfma_f32_16x16x32_bf16(cfC, bf, accY[nt], 0, 0, 0);
      }
      if (q < 15)  // prefetch next pair's w_out fragment
        cfC = *(const short8*)(wsC + (((p + 1) * 4 + wave) * 64 + lane) * 8);
    }

    // rotate dwconv weights
    if (q < 15) {
#pragma unroll
      for (int u = 0; u < 9; ++u) wdC[u] = wdN[u];
      bdC = bdN;
    }
  }

  // ---- epilogue ----
  {
    f32x4 bo;
#pragma unroll
    for (int r = 0; r < 4; ++r) bo[r] = b_out[wave * 16 + lg * 4 + r];
#pragma unroll
    for (int nt = 0; nt < 8; ++nt)
#pragma unroll
      for (int r = 0; r < 4; ++r) accY[nt][r] += bo[r];
  }

  if (t == 0) s_flag = 1;
  __syncthreads();
  {
    int ok = 1;
    const float* kc = ws;
#pragma unroll
    for (int j = 0; j < 16; ++j) {
      int idx = t * 16 + j;
      float e = ((idx & 63) == 0) ? 1.f : 0.f;
      ok &= (fabsf(kc[idx] - e) <= 1e-5f) ? 1 : 0;
    }
    if (!ok) s_flag = 0;
  }
  __syncthreads();

  const int o = wave * 16 + lg * 4;
  if (s_flag) {  // identity spectral filter: direct store
#pragma unroll
    for (int nt = 0; nt < 8; ++nt) {
      float* op = out + (((size_t)(b * 64 + o)) * IH + gy0 + nt) * IW + gx0 + l15;
#pragma unroll
      for (int r = 0; r < 4; ++r) op[(size_t)r * IH * IW] = accY[nt][r];
    }
    return;
  }

  // general path: per-patch circular convolution with kc (correct for any filter)
  float* YS = (float*)smem;  // [32][132]
  for (int half = 0; half < 2; ++half) {
    __syncthreads();
    if ((wave >> 1) == half) {
      int c32 = (wave & 1) * 16 + lg * 4;
#pragma unroll
      for (int nt = 0; nt < 8; ++nt)
#pragma unroll
        for (int r = 0; r < 4; ++r) YS[(c32 + r) * 132 + nt * 16 + l15] = accY[nt][r];
    }
    __syncthreads();
    if (t < 64) {  // 32 ch x 2 patches (8 wide each)
      int o32 = t >> 1, oo = half * 32 + o32, qd = t & 1;
      const float* kp = ws + oo * 64;
      int px0 = qd * 8;
      const float* row = YS + o32 * 132;
      for (int i = 0; i < 8; ++i)
        for (int j = 0; j < 8; ++j) {
          float acc = 0.f;
          for (int a_ = 0; a_ < 8; ++a_)
            for (int b_ = 0; b_ < 8; ++b_)
              acc += kp[a_ * 8 + b_] *
                     row[((i - a_) & 7) * 16 + px0 + ((j - b_) & 7)];
          out[(((size_t)(b * 64 + oo)) * IH + gy0 + i) * IW + gx0 + px0 + j] = acc;
        }
    }
  }
}

extern "C" void kernel_launch(void* const* d_in, const int* in_sizes, int n_in,
                              void* d_out, int out_size, void* d_ws, size_t ws_size,
                              hipStream_t stream) {
  const float* x = (const float*)d_in[0];
  const float* w_in = (const float*)d_in[1];
  const float* b_in = (const float*)d_in[2];
  const float* w_dw = (const float*)d_in[3];
  const float* b_dw = (const float*)d_in[4];
  const float* w_out = (const float*)d_in[5];
  const float* b_out = (const float*)d_in[6];
  const float* fftf = (const float*)d_in[7];
  float* out = (float*)d_out;
  float* ws = (float*)d_ws;

  edffn_prep<<<160, 64, 0, stream>>>(fftf, w_in, w_out, ws);
  dim3 grid(IW / TX, IH / TY, 4);
  edffn_main<<<grid, 256, 0, stream>>>(x, b_in, w_dw, b_dw, b_out, ws, out);
}

// Round 12
// 156.411 us; speedup vs baseline: 1.1742x; 1.1742x over previous
//
#include <hip/hip_runtime.h>
#include <math.h>

typedef __attribute__((ext_vector_type(8))) short short8;
typedef __attribute__((ext_vector_type(4))) float f32x4;
typedef __attribute__((ext_vector_type(2))) float f32x2;

#define TILE 16
#define IH 256
#define IW 256

// ws byte layout: [0,16384) kc f32[64][64]; [16384,81920) wsA frags ushort;
//                 [81920,114688) wsC frags ushort
#define WSA_OFF 16384
#define WSC_OFF 81920

// LDS layout (bytes):
//   H: [16 ch][1456] (18 rows x 80B + 16B pad); px = packed f16 (h1,h2) 4B
//   G: @23296: [256 px][64B = 4 granules of 16B, XOR gi = (ch>>3)^(oy&3)]
//   slow-path YS f32[32][260] (33280 B) overlays @0
#define H_STRIDE 1456
#define G_OFF 23296
#define SMEM_BYTES 39680

#define SP2(c) ((f32x2){(c), (c)})

__device__ __forceinline__ unsigned short f2bf(float f) {
  unsigned int u = __builtin_bit_cast(unsigned int, f);
  u = (u + 0x7FFFu + ((u >> 16) & 1u)) >> 16;
  return (unsigned short)u;
}

__global__ void edffn_prep(const float* __restrict__ fftf,
                           const float* __restrict__ w_in,
                           const float* __restrict__ w_out,
                           float* __restrict__ ws) {
  int blk = blockIdx.x, t = threadIdx.x;
  if (blk < 64) {
    // kc = irfft2 of the (real, symmetric) full-spectrum multiplier
    int a = t >> 3, bb = t & 7;
    const float c0 = 0.70710678118654752f;
    const float ctab[8] = {1.f, c0, 0.f, -c0, -1.f, -c0, 0.f, c0};
    const float* F = fftf + blk * 40;  // [8][5]
    float acc = 0.f;
    for (int k1 = 0; k1 < 8; ++k1)
      for (int k2 = 0; k2 < 8; ++k2) {
        float f = (k2 <= 4) ? F[k1 * 5 + k2] : F[((8 - k1) & 7) * 5 + (8 - k2)];
        acc += f * ctab[(k1 * a + k2 * bb) & 7];
      }
    ws[blk * 64 + t] = acc * (1.f / 64.f);
  } else if (blk < 128) {
    // w_in A-fragments: [chunk q=0..15][s=0,1][ks=0,1][lane][8]
    int b2 = blk - 64;
    int q = b2 >> 2, s = (b2 >> 1) & 1, ks = b2 & 1;
    int row = (s ? 256 : 0) + q * 16 + (t & 15);
    unsigned short* dst =
        (unsigned short*)((unsigned char*)ws + WSA_OFF) + (((q * 2 + s) * 2 + ks) * 64 + t) * 8;
    for (int j = 0; j < 8; ++j) {
      int k = ks * 32 + (t >> 4) * 8 + j;
      dst[j] = f2bf(w_in[row * 64 + k]);
    }
  } else {
    // w_out A-fragments: [pair p=0..7][mtile=0..3][lane][8]
    int b3 = blk - 128;
    int p = b3 >> 2, mt = b3 & 3;
    int row = mt * 16 + (t & 15);
    unsigned short* dst =
        (unsigned short*)((unsigned char*)ws + WSC_OFF) + ((p * 4 + mt) * 64 + t) * 8;
    for (int j = 0; j < 8; ++j) {
      int k = p * 32 + (t >> 4) * 8 + j;
      dst[j] = f2bf(w_out[row * 256 + k]);
    }
  }
}

__global__ __launch_bounds__(256, 2) void edffn_main(
    const float* __restrict__ x, const float* __restrict__ b_in,
    const float* __restrict__ w_dw, const float* __restrict__ b_dw,
    const float* __restrict__ b_out, const float* __restrict__ ws,
    float* __restrict__ out) {
  __shared__ __align__(16) unsigned char smem[SMEM_BYTES];
  __shared__ int s_flag;
  const int t = threadIdx.x;
  const int lane = t & 63, wave = t >> 6;
  const int l15 = lane & 15, lg = lane >> 4;
  const int gx0 = blockIdx.x * TILE, gy0 = blockIdx.y * TILE;
  const int b = blockIdx.z;
  const unsigned short* wsA = (const unsigned short*)((const unsigned char*)ws + WSA_OFF);
  const unsigned short* wsC = (const unsigned short*)((const unsigned char*)ws + WSC_OFF);

  // ---- stage-A B-fragments (x halo, bf16) held in registers across all chunks ----
  short8 xf[6][2];
  int haddr[6];
  unsigned vmask = 0, imask = 0;
  const float* xb = x + (size_t)b * 64 * 65536;
#pragma unroll
  for (int i = 0; i < 6; ++i) {
    int nt = wave + 4 * i;  // wave0: 0,4,..,20 ; waves1-3: last invalid
    int n = nt * 16 + l15;
    int hy = n / 18;
    int hx = n - hy * 18;
    int gy = gy0 + hy - 1, gx = gx0 + hx - 1;
    int vnt = (nt < 21) & (n < 324);
    int inb = vnt & (gy >= 0) & (gy < IH) & (gx >= 0) & (gx < IW);
    haddr[i] = hy * 80 + hx * 4;
    vmask |= (unsigned)vnt << i;
    imask |= (unsigned)inb << i;
    int gyc = min(max(gy, 0), IH - 1), gxc = min(max(gx, 0), IW - 1);
    const float* xp = xb + (size_t)gyc * IW + gxc;
#pragma unroll
    for (int ks = 0; ks < 2; ++ks) {
#pragma unroll
      for (int j = 0; j < 8; ++j) {
        int k = ks * 32 + lg * 8 + j;
        unsigned short bf = f2bf(xp[(size_t)k * 65536]);
        xf[i][ks][j] = (short)(inb ? bf : (unsigned short)0);
      }
    }
  }

  f32x4 accY[16];
#pragma unroll
  for (int i = 0; i < 16; ++i) accY[i] = (f32x4){0.f, 0.f, 0.f, 0.f};

  const int cp_dw = t & 15;  // channel-in-chunk (wave spans all 16 -> 4-way G writes)
  const int oy_dw = t >> 4;  // output row 0..15

  auto loadWD = [&](int qq, unsigned (&wd)[9], unsigned& bd) {
    const int cg1 = qq * 16 + cp_dw, cg2 = 256 + qq * 16 + cp_dw;
#pragma unroll
    for (int u = 0; u < 9; ++u) {
      float w1 = w_dw[cg1 * 9 + u], w2 = w_dw[cg2 * 9 + u];
      asm("v_cvt_pkrtz_f16_f32 %0, %1, %2" : "=v"(wd[u]) : "v"(w1), "v"(w2));
    }
    float b1 = b_dw[cg1], b2 = b_dw[cg2];
    asm("v_cvt_pkrtz_f16_f32 %0, %1, %2" : "=v"(bd) : "v"(b1), "v"(b2));
  };

  unsigned wdC[9], wdN[9], bdC, bdN;
  short8 cfC;
  loadWD(0, wdC, bdC);
  cfC = *(const short8*)(wsC + ((0 * 4 + wave) * 64 + lane) * 8);

  for (int q = 0; q < 16; ++q) {
    // ---- stage A: H(32 gated-ch x 324 px) via MFMA; packed f16 (h1,h2) store ----
    {
      short8 af[2][2];
#pragma unroll
      for (int s = 0; s < 2; ++s)
#pragma unroll
        for (int ks = 0; ks < 2; ++ks)
          af[s][ks] = *(const short8*)(wsA + (((q * 2 + s) * 2 + ks) * 64 + lane) * 8);
      float bin[2][4];
#pragma unroll
      for (int s = 0; s < 2; ++s)
#pragma unroll
        for (int r = 0; r < 4; ++r) bin[s][r] = b_in[(s ? 256 : 0) + q * 16 + lg * 4 + r];
#pragma unroll
      for (int i = 0; i < 6; ++i) {
        if (wave + 4 * i < 21) {  // wave-uniform
          f32x4 acc0 = {0.f, 0.f, 0.f, 0.f}, acc1 = {0.f, 0.f, 0.f, 0.f};
          acc0 = __builtin_amdgcn_mfma_f32_16x16x32_bf16(af[0][0], xf[i][0], acc0, 0, 0, 0);
          acc0 = __builtin_amdgcn_mfma_f32_16x16x32_bf16(af[0][1], xf[i][1], acc0, 0, 0, 0);
          acc1 = __builtin_amdgcn_mfma_f32_16x16x32_bf16(af[1][0], xf[i][0], acc1, 0, 0, 0);
          acc1 = __builtin_amdgcn_mfma_f32_16x16x32_bf16(af[1][1], xf[i][1], acc1, 0, 0, 0);
          if ((vmask >> i) & 1u) {  // per-lane mask on writes only (MFMA stays convergent)
            unsigned keep = (imask >> i) & 1u;
#pragma unroll
            for (int r = 0; r < 4; ++r) {
              float v0 = acc0[r] + bin[0][r];
              float v1 = acc1[r] + bin[1][r];
              unsigned pk;
              asm("v_cvt_pkrtz_f16_f32 %0, %1, %2" : "=v"(pk) : "v"(v0), "v"(v1));
              pk = keep ? pk : 0u;  // SAME pad: h=0 outside image
              *(unsigned*)(smem + (lg * 4 + r) * H_STRIDE + haddr[i]) = pk;
            }
          }
        }
      }
    }
    // next chunk's dwconv weights: full dwconv+barrier to land
    if (q < 15) loadWD(q + 1, wdN, bdN);
    __syncthreads();

    // ---- dwconv 3x3 + exact GELU gate (thread = (cp=t&15, oy=t>>4); pk f16) ----
    {
      const int cp = cp_dw, oy = oy_dw;
      unsigned a[16];
#pragma unroll
      for (int j = 0; j < 16; ++j) a[j] = bdC;
#pragma unroll
      for (int dy = 0; dy < 3; ++dy) {
        const uint4* rp = (const uint4*)(smem + cp * H_STRIDE + (oy + dy) * 80);
        uint4 r0 = rp[0], r1 = rp[1], r2 = rp[2], r3 = rp[3];
        uint2 r4 = ((const uint2*)rp)[8];
        unsigned e[18] = {r0.x, r0.y, r0.z, r0.w, r1.x, r1.y, r1.z, r1.w,
                          r2.x, r2.y, r2.z, r2.w, r3.x, r3.y, r3.z, r3.w,
                          r4.x, r4.y};
#pragma unroll
        for (int ox = 0; ox < 16; ++ox) {
#pragma unroll
          for (int dx = 0; dx < 3; ++dx)
            asm("v_pk_fma_f16 %0, %1, %2, %0"
                : "+v"(a[ox])
                : "v"(wdC[dy * 3 + dx]), "v"(e[ox + dx]));
        }
      }
      const int c2 = (q & 1) * 16 + cp;
      const int gi = (c2 >> 3) ^ (oy & 3);  // 16B-granule XOR swizzle (involution)
      unsigned short* Gp =
          (unsigned short*)(smem + G_OFF) + oy * 16 * 32 + gi * 8 + (c2 & 7);
      // unpack, exact GELU(h1)*h2 pk-paired across ox
#pragma unroll
      for (int j = 0; j < 8; ++j) {
        unsigned a0 = a[2 * j], a1 = a[2 * j + 1];
        unsigned a0h = a0 >> 16, a1h = a1 >> 16;
        f32x2 u, v;
        asm("v_cvt_f32_f16 %0, %1" : "=v"(u[0]) : "v"(a0));
        asm("v_cvt_f32_f16 %0, %1" : "=v"(u[1]) : "v"(a1));
        asm("v_cvt_f32_f16 %0, %1" : "=v"(v[0]) : "v"(a0h));
        asm("v_cvt_f32_f16 %0, %1" : "=v"(v[1]) : "v"(a1h));
        f32x2 z = u * 0.70710678118654752f;
        f32x2 z2 = z * z;
        f32x2 erfv;
        if (__builtin_expect(fmaxf(z2[0], z2[1]) > 0.16f, 0)) {
          erfv[0] = erff(z[0]);  // exact fallback (not taken for this data)
          erfv[1] = erff(z[1]);
        } else {  // 5-term odd Taylor, |err|<3e-8 on |z|<=0.4
          f32x2 p = __builtin_elementwise_fma(z2, SP2(1.f / 216.f), SP2(-1.f / 42.f));
          p = __builtin_elementwise_fma(z2, p, SP2(1.f / 10.f));
          p = __builtin_elementwise_fma(z2, p, SP2(-1.f / 3.f));
          p = __builtin_elementwise_fma(z2, p, SP2(1.f));
          erfv = 1.12837916709551257f * (z * p);
        }
        f32x2 tt = __builtin_elementwise_fma(erfv, SP2(0.5f), SP2(0.5f));  // (1+erf)/2
        f32x2 g = (u * tt) * v;
        Gp[(2 * j) * 32] = f2bf(g[0]);
        Gp[(2 * j + 1) * 32] = f2bf(g[1]);
      }
    }
    __syncthreads();

    // ---- stage C every 2 chunks: y += w_out[:,32] @ G ----
    if (q & 1) {
      const int p = q >> 1;
      const unsigned short* G = (const unsigned short*)(smem + G_OFF);
#pragma unroll
      for (int nt = 0; nt < 16; ++nt) {
        int g = lg ^ (nt & 3);  // reader-side XOR (nt uniform per instr)
        int n = nt * 16 + l15;
        short8 bf = *(const short8*)(G + n * 32 + g * 8);
        accY[nt] = __builtin_amdgcn_mfma_f32_16x16x32_bf16(cfC, bf, accY[nt], 0, 0, 0);
      }
      if (q < 15)  // prefetch next pair's w_out fragment
        cfC = *(const short8*)(wsC + (((p + 1) * 4 + wave) * 64 + lane) * 8);
    }

    // rotate dwconv weights
    if (q < 15) {
#pragma unroll
      for (int u = 0; u < 9; ++u) wdC[u] = wdN[u];
      bdC = bdN;
    }
  }

  // ---- epilogue ----
  {
    f32x4 bo;
#pragma unroll
    for (int r = 0; r < 4; ++r) bo[r] = b_out[wave * 16 + lg * 4 + r];
#pragma unroll
    for (int nt = 0; nt < 16; ++nt)
#pragma unroll
      for (int r = 0; r < 4; ++r) accY[nt][r] += bo[r];
  }

  if (t == 0) s_flag = 1;
  __syncthreads();
  {
    int ok = 1;
    const float* kc = ws;
#pragma unroll
    for (int j = 0; j < 16; ++j) {
      int idx = t * 16 + j;
      float e = ((idx & 63) == 0) ? 1.f : 0.f;
      ok &= (fabsf(kc[idx] - e) <= 1e-5f) ? 1 : 0;
    }
    if (!ok) s_flag = 0;
  }
  __syncthreads();

  const int o = wave * 16 + lg * 4;
  if (s_flag) {  // identity spectral filter: direct store
#pragma unroll
    for (int nt = 0; nt < 16; ++nt) {
      float* op = out + (((size_t)(b * 64 + o)) * IH + gy0 + nt) * IW + gx0 + l15;
#pragma unroll
      for (int r = 0; r < 4; ++r) op[(size_t)r * IH * IW] = accY[nt][r];
    }
    return;
  }

  // general path: per-patch circular convolution with kc (correct for any filter)
  float* YS = (float*)smem;  // [32][260]
  for (int half = 0; half < 2; ++half) {
    __syncthreads();
    if ((wave >> 1) == half) {
      int c32 = (wave & 1) * 16 + lg * 4;
#pragma unroll
      for (int nt = 0; nt < 16; ++nt)
#pragma unroll
        for (int r = 0; r < 4; ++r) YS[(c32 + r) * 260 + nt * 16 + l15] = accY[nt][r];
    }
    __syncthreads();
    if (t < 128) {
      int o32 = t >> 2, oo = half * 32 + o32, qd = t & 3;
      const float* kp = ws + oo * 64;
      int py0 = (qd >> 1) * 8, px0 = (qd & 1) * 8;
      const float* row = YS + o32 * 260;
      for (int i = 0; i < 8; ++i)
        for (int j = 0; j < 8; ++j) {
          float acc = 0.f;
          for (int a_ = 0; a_ < 8; ++a_)
            for (int b_ = 0; b_ < 8; ++b_)
              acc += kp[a_ * 8 + b_] *
                     row[(py0 + ((i - a_) & 7)) * 16 + px0 + ((j - b_) & 7)];
          out[(((size_t)(b * 64 + oo)) * IH + gy0 + py0 + i) * IW + gx0 + px0 + j] = acc;
        }
    }
  }
}

extern "C" void kernel_launch(void* const* d_in, const int* in_sizes, int n_in,
                              void* d_out, int out_size, void* d_ws, size_t ws_size,
                              hipStream_t stream) {
  const float* x = (const float*)d_in[0];
  const float* w_in = (const float*)d_in[1];
  const float* b_in = (const float*)d_in[2];
  const float* w_dw = (const float*)d_in[3];
  const float* b_dw = (const float*)d_in[4];
  const float* w_out = (const float*)d_in[5];
  const float* b_out = (const float*)d_in[6];
  const float* fftf = (const float*)d_in[7];
  float* out = (float*)d_out;
  float* ws = (float*)d_ws;

  edffn_prep<<<160, 64, 0, stream>>>(fftf, w_in, w_out, ws);
  dim3 grid(IW / TILE, IH / TILE, 4);
  edffn_main<<<grid, 256, 0, stream>>>(x, b_in, w_dw, b_dw, b_out, ws, out);
}

// Round 13
// 150.150 us; speedup vs baseline: 1.2231x; 1.0417x over previous
//
#include <hip/hip_runtime.h>
#include <math.h>

typedef __attribute__((ext_vector_type(8))) short short8;
typedef __attribute__((ext_vector_type(4))) float f32x4;
typedef __attribute__((ext_vector_type(2))) float f32x2;
typedef _Float16 f16x8 __attribute__((ext_vector_type(8)));

#define TILE 16
#define IH 256
#define IW 256

// ws byte layout: [0,16384) kc f32[64][64]; [16384,81920) wsA frags ushort (bf16);
//                 [81920,114688) wsC frags ushort (f16)
#define WSA_OFF 16384
#define WSC_OFF 81920

// LDS layout (bytes):
//   H: [16 ch][1456] (18 rows x 80B + 16B pad); px = packed f16 (h1,h2) 4B
//   G: @23296: DOUBLE-buffered, each [256 px][64B = 4 granules, XOR gi=(ch>>3)^(oy&3)], f16
//   slow-path YS f32[32][260] (33280 B) overlays @0
#define H_STRIDE 1456
#define G_OFF 23296
#define G_BUF 16384
#define SMEM_BYTES 56064

__device__ __forceinline__ unsigned short f2bf(float f) {
  unsigned int u = __builtin_bit_cast(unsigned int, f);
  u = (u + 0x7FFFu + ((u >> 16) & 1u)) >> 16;
  return (unsigned short)u;
}

__global__ void edffn_prep(const float* __restrict__ fftf,
                           const float* __restrict__ w_in,
                           const float* __restrict__ w_out,
                           float* __restrict__ ws) {
  int blk = blockIdx.x, t = threadIdx.x;
  if (blk < 64) {
    // kc = irfft2 of the (real, symmetric) full-spectrum multiplier
    int a = t >> 3, bb = t & 7;
    const float c0 = 0.70710678118654752f;
    const float ctab[8] = {1.f, c0, 0.f, -c0, -1.f, -c0, 0.f, c0};
    const float* F = fftf + blk * 40;  // [8][5]
    float acc = 0.f;
    for (int k1 = 0; k1 < 8; ++k1)
      for (int k2 = 0; k2 < 8; ++k2) {
        float f = (k2 <= 4) ? F[k1 * 5 + k2] : F[((8 - k1) & 7) * 5 + (8 - k2)];
        acc += f * ctab[(k1 * a + k2 * bb) & 7];
      }
    ws[blk * 64 + t] = acc * (1.f / 64.f);
  } else if (blk < 128) {
    // w_in A-fragments (bf16): [chunk q=0..15][s=0,1][ks=0,1][lane][8]
    int b2 = blk - 64;
    int q = b2 >> 2, s = (b2 >> 1) & 1, ks = b2 & 1;
    int row = (s ? 256 : 0) + q * 16 + (t & 15);
    unsigned short* dst =
        (unsigned short*)((unsigned char*)ws + WSA_OFF) + (((q * 2 + s) * 2 + ks) * 64 + t) * 8;
    for (int j = 0; j < 8; ++j) {
      int k = ks * 32 + (t >> 4) * 8 + j;
      dst[j] = f2bf(w_in[row * 64 + k]);
    }
  } else {
    // w_out A-fragments (f16): [pair p=0..7][mtile=0..3][lane][8]
    int b3 = blk - 128;
    int p = b3 >> 2, mt = b3 & 3;
    int row = mt * 16 + (t & 15);
    unsigned short* dst =
        (unsigned short*)((unsigned char*)ws + WSC_OFF) + ((p * 4 + mt) * 64 + t) * 8;
    for (int j = 0; j < 8; ++j) {
      int k = p * 32 + (t >> 4) * 8 + j;
      _Float16 hv = (_Float16)w_out[row * 256 + k];
      dst[j] = __builtin_bit_cast(unsigned short, hv);
    }
  }
}

__global__ __launch_bounds__(256, 2) void edffn_main(
    const float* __restrict__ x, const float* __restrict__ b_in,
    const float* __restrict__ w_dw, const float* __restrict__ b_dw,
    const float* __restrict__ b_out, const float* __restrict__ ws,
    float* __restrict__ out) {
  __shared__ __align__(16) unsigned char smem[SMEM_BYTES];
  __shared__ int s_flag;
  const int t = threadIdx.x;
  const int lane = t & 63, wave = t >> 6;
  const int l15 = lane & 15, lg = lane >> 4;
  const int gx0 = blockIdx.x * TILE, gy0 = blockIdx.y * TILE;
  const int b = blockIdx.z;
  const unsigned short* wsA = (const unsigned short*)((const unsigned char*)ws + WSA_OFF);
  const unsigned short* wsC = (const unsigned short*)((const unsigned char*)ws + WSC_OFF);

  // ---- stage-A B-fragments (x halo, bf16) held in registers across all chunks ----
  short8 xf[6][2];
  int haddr[6];
  unsigned vmask = 0, imask = 0;
  const float* xb = x + (size_t)b * 64 * 65536;
#pragma unroll
  for (int i = 0; i < 6; ++i) {
    int nt = wave + 4 * i;  // wave0: 0,4,..,20 ; waves1-3: last invalid
    int n = nt * 16 + l15;
    int hy = n / 18;
    int hx = n - hy * 18;
    int gy = gy0 + hy - 1, gx = gx0 + hx - 1;
    int vnt = (nt < 21) & (n < 324);
    int inb = vnt & (gy >= 0) & (gy < IH) & (gx >= 0) & (gx < IW);
    haddr[i] = hy * 80 + hx * 4;
    vmask |= (unsigned)vnt << i;
    imask |= (unsigned)inb << i;
    int gyc = min(max(gy, 0), IH - 1), gxc = min(max(gx, 0), IW - 1);
    const float* xp = xb + (size_t)gyc * IW + gxc;
#pragma unroll
    for (int ks = 0; ks < 2; ++ks) {
#pragma unroll
      for (int j = 0; j < 8; ++j) {
        int k = ks * 32 + lg * 8 + j;
        unsigned short bf = f2bf(xp[(size_t)k * 65536]);
        xf[i][ks][j] = (short)(inb ? bf : (unsigned short)0);
      }
    }
  }

  f32x4 accY[16];
#pragma unroll
  for (int i = 0; i < 16; ++i) accY[i] = (f32x4){0.f, 0.f, 0.f, 0.f};

  const int cp_dw = t & 15;  // channel-in-chunk (wave spans all 16)
  const int oy_dw = t >> 4;  // output row 0..15

  auto loadWD = [&](int qq, unsigned (&wd)[9], unsigned& bd) {
    const int cg1 = qq * 16 + cp_dw, cg2 = 256 + qq * 16 + cp_dw;
#pragma unroll
    for (int u = 0; u < 9; ++u) {
      float w1 = w_dw[cg1 * 9 + u], w2 = w_dw[cg2 * 9 + u];
      asm("v_cvt_pkrtz_f16_f32 %0, %1, %2" : "=v"(wd[u]) : "v"(w1), "v"(w2));
    }
    float b1 = b_dw[cg1], b2 = b_dw[cg2];
    asm("v_cvt_pkrtz_f16_f32 %0, %1, %2" : "=v"(bd) : "v"(b1), "v"(b2));
  };

  // packed-f16 GELU constants
#define PKC(nm, val)                                                        \
  unsigned nm;                                                              \
  {                                                                         \
    float fv = (val);                                                       \
    asm("v_cvt_pkrtz_f16_f32 %0, %1, %1" : "=v"(nm) : "v"(fv));             \
  }
  PKC(kSQ, 0.70710678f)
  PKC(kC216, 1.f / 216.f)
  PKC(kCm42, -1.f / 42.f)
  PKC(kC10, 0.1f)
  PKC(kCm3, -1.f / 3.f)
  PKC(kOne, 1.0f)
  PKC(kHalf, 0.5f)
  PKC(kErf, 1.12837917f)
#undef PKC

  unsigned wdC[9], wdN[9], bdC, bdN;
  f16x8 cfC;
  loadWD(0, wdC, bdC);
  cfC = *(const f16x8*)(wsC + ((0 * 4 + wave) * 64 + lane) * 8);

  for (int q = 0; q < 16; ++q) {
    // ---- stage A: H(32 gated-ch x 324 px) via MFMA; packed f16 (h1,h2) store ----
    {
      short8 af[2][2];
#pragma unroll
      for (int s = 0; s < 2; ++s)
#pragma unroll
        for (int ks = 0; ks < 2; ++ks)
          af[s][ks] = *(const short8*)(wsA + (((q * 2 + s) * 2 + ks) * 64 + lane) * 8);
      float bin[2][4];
#pragma unroll
      for (int s = 0; s < 2; ++s)
#pragma unroll
        for (int r = 0; r < 4; ++r) bin[s][r] = b_in[(s ? 256 : 0) + q * 16 + lg * 4 + r];
#pragma unroll
      for (int i = 0; i < 6; ++i) {
        if (wave + 4 * i < 21) {  // wave-uniform
          f32x4 acc0 = {0.f, 0.f, 0.f, 0.f}, acc1 = {0.f, 0.f, 0.f, 0.f};
          acc0 = __builtin_amdgcn_mfma_f32_16x16x32_bf16(af[0][0], xf[i][0], acc0, 0, 0, 0);
          acc0 = __builtin_amdgcn_mfma_f32_16x16x32_bf16(af[0][1], xf[i][1], acc0, 0, 0, 0);
          acc1 = __builtin_amdgcn_mfma_f32_16x16x32_bf16(af[1][0], xf[i][0], acc1, 0, 0, 0);
          acc1 = __builtin_amdgcn_mfma_f32_16x16x32_bf16(af[1][1], xf[i][1], acc1, 0, 0, 0);
          if ((vmask >> i) & 1u) {  // per-lane mask on writes only (MFMA stays convergent)
            unsigned keep = (imask >> i) & 1u;
#pragma unroll
            for (int r = 0; r < 4; ++r) {
              float v0 = acc0[r] + bin[0][r];
              float v1 = acc1[r] + bin[1][r];
              unsigned pk;
              asm("v_cvt_pkrtz_f16_f32 %0, %1, %2" : "=v"(pk) : "v"(v0), "v"(v1));
              pk = keep ? pk : 0u;  // SAME pad: h=0 outside image
              *(unsigned*)(smem + (lg * 4 + r) * H_STRIDE + haddr[i]) = pk;
            }
          }
        }
      }
    }
    if (q < 15) loadWD(q + 1, wdN, bdN);
    __syncthreads();

    // ---- stage C (merged): pair pc=(q>>1)-1 from G[pc&1]; overlaps dwconv below ----
    if (q >= 2 && !(q & 1)) {
      const int pc = (q >> 1) - 1;
      const unsigned short* G =
          (const unsigned short*)(smem + G_OFF + (pc & 1) * G_BUF);
#pragma unroll
      for (int nt = 0; nt < 16; ++nt) {
        int g = lg ^ (nt & 3);  // reader-side XOR (nt uniform per instr)
        int n = nt * 16 + l15;
        f16x8 bf = *(const f16x8*)(G + n * 32 + g * 8);
        accY[nt] = __builtin_amdgcn_mfma_f32_16x16x32_f16(cfC, bf, accY[nt], 0, 0, 0);
      }
      cfC = *(const f16x8*)(wsC + (((pc + 1) * 4 + wave) * 64 + lane) * 8);
    }

    // ---- dwconv 3x3 + GELU gate, all packed f16; writes G[(q>>1)&1] ----
    {
      const int cp = cp_dw, oy = oy_dw;
      unsigned a[16];
#pragma unroll
      for (int j = 0; j < 16; ++j) a[j] = bdC;
#pragma unroll
      for (int dy = 0; dy < 3; ++dy) {
        const uint4* rp = (const uint4*)(smem + cp * H_STRIDE + (oy + dy) * 80);
        uint4 r0 = rp[0], r1 = rp[1], r2 = rp[2], r3 = rp[3];
        uint2 r4 = ((const uint2*)rp)[8];
        unsigned e[18] = {r0.x, r0.y, r0.z, r0.w, r1.x, r1.y, r1.z, r1.w,
                          r2.x, r2.y, r2.z, r2.w, r3.x, r3.y, r3.z, r3.w,
                          r4.x, r4.y};
#pragma unroll
        for (int ox = 0; ox < 16; ++ox) {
#pragma unroll
          for (int dx = 0; dx < 3; ++dx)
            asm("v_pk_fma_f16 %0, %1, %2, %0"
                : "+v"(a[ox])
                : "v"(wdC[dy * 3 + dx]), "v"(e[ox + dx]));
        }
      }
      const int c2 = (q & 1) * 16 + cp;
      const int gi = (c2 >> 3) ^ (oy & 3);  // 16B-granule XOR swizzle (involution)
      unsigned short* Gp = (unsigned short*)(smem + G_OFF + ((q >> 1) & 1) * G_BUF) +
                           oy * 16 * 32 + gi * 8 + (c2 & 7);
      // packed-f16 GELU: u = (h1,h1') lows, v = (h2,h2') highs per ox pair
      unsigned umax = 0;
      unsigned gw[8];
#pragma unroll
      for (int j = 0; j < 8; ++j) {
        unsigned a0 = a[2 * j], a1 = a[2 * j + 1];
        unsigned u = __builtin_amdgcn_perm(a1, a0, 0x05040100u);
        unsigned v = __builtin_amdgcn_perm(a1, a0, 0x07060302u);
        unsigned uabs = u & 0x7FFF7FFFu;
        asm("v_pk_max_f16 %0, %1, %2" : "=v"(umax) : "v"(umax), "v"(uabs));
        unsigned z, z2, p, erfv, tt, g;
        asm("v_pk_mul_f16 %0, %1, %2" : "=v"(z) : "v"(u), "v"(kSQ));
        asm("v_pk_mul_f16 %0, %1, %2" : "=v"(z2) : "v"(z), "v"(z));
        asm("v_pk_fma_f16 %0, %1, %2, %3" : "=v"(p) : "v"(z2), "v"(kC216), "v"(kCm42));
        asm("v_pk_fma_f16 %0, %1, %2, %3" : "=v"(p) : "v"(z2), "v"(p), "v"(kC10));
        asm("v_pk_fma_f16 %0, %1, %2, %3" : "=v"(p) : "v"(z2), "v"(p), "v"(kCm3));
        asm("v_pk_fma_f16 %0, %1, %2, %3" : "=v"(p) : "v"(z2), "v"(p), "v"(kOne));
        asm("v_pk_mul_f16 %0, %1, %2" : "=v"(erfv) : "v"(z), "v"(p));
        asm("v_pk_mul_f16 %0, %1, %2" : "=v"(erfv) : "v"(erfv), "v"(kErf));
        asm("v_pk_fma_f16 %0, %1, %2, %2" : "=v"(tt) : "v"(erfv), "v"(kHalf));
        asm("v_pk_mul_f16 %0, %1, %2" : "=v"(g) : "v"(u), "v"(tt));
        asm("v_pk_mul_f16 %0, %1, %2" : "=v"(g) : "v"(g), "v"(v));
        gw[j] = g;
      }
      {  // exact fallback if any |z|>0.4  (cold; preserves correctness for any data)
        float m0, m1;
        unsigned uh = umax >> 16;
        asm("v_cvt_f32_f16 %0, %1" : "=v"(m0) : "v"(umax));
        asm("v_cvt_f32_f16 %0, %1" : "=v"(m1) : "v"(uh));
        if (__builtin_expect(fmaxf(m0, m1) > 0.565685f, 0)) {
#pragma unroll
          for (int j = 0; j < 8; ++j) {
            float g01[2];
#pragma unroll
            for (int kx = 0; kx < 2; ++kx) {
              unsigned aw = a[2 * j + kx], ah = aw >> 16;
              float hu, hv2;
              asm("v_cvt_f32_f16 %0, %1" : "=v"(hu) : "v"(aw));
              asm("v_cvt_f32_f16 %0, %1" : "=v"(hv2) : "v"(ah));
              g01[kx] = 0.5f * hu * (1.f + erff(hu * 0.70710678f)) * hv2;
            }
            unsigned pk;
            asm("v_cvt_pkrtz_f16_f32 %0, %1, %2" : "=v"(pk) : "v"(g01[0]), "v"(g01[1]));
            gw[j] = pk;
          }
        }
      }
#pragma unroll
      for (int j = 0; j < 8; ++j) {
        Gp[(2 * j) * 32] = (unsigned short)gw[j];
        Gp[(2 * j + 1) * 32] = (unsigned short)(gw[j] >> 16);
      }
    }
    __syncthreads();

    // rotate dwconv weights
    if (q < 15) {
#pragma unroll
      for (int u = 0; u < 9; ++u) wdC[u] = wdN[u];
      bdC = bdN;
    }
  }

  // ---- final stage C: pair 7 from G[1] ----
  {
    const unsigned short* G = (const unsigned short*)(smem + G_OFF + G_BUF);
#pragma unroll
    for (int nt = 0; nt < 16; ++nt) {
      int g = lg ^ (nt & 3);
      int n = nt * 16 + l15;
      f16x8 bf = *(const f16x8*)(G + n * 32 + g * 8);
      accY[nt] = __builtin_amdgcn_mfma_f32_16x16x32_f16(cfC, bf, accY[nt], 0, 0, 0);
    }
  }

  // ---- epilogue ----
  {
    f32x4 bo;
#pragma unroll
    for (int r = 0; r < 4; ++r) bo[r] = b_out[wave * 16 + lg * 4 + r];
#pragma unroll
    for (int nt = 0; nt < 16; ++nt)
#pragma unroll
      for (int r = 0; r < 4; ++r) accY[nt][r] += bo[r];
  }

  if (t == 0) s_flag = 1;
  __syncthreads();
  {
    int ok = 1;
    const float* kc = ws;
#pragma unroll
    for (int j = 0; j < 16; ++j) {
      int idx = t * 16 + j;
      float e = ((idx & 63) == 0) ? 1.f : 0.f;
      ok &= (fabsf(kc[idx] - e) <= 1e-5f) ? 1 : 0;
    }
    if (!ok) s_flag = 0;
  }
  __syncthreads();

  const int o = wave * 16 + lg * 4;
  if (s_flag) {  // identity spectral filter: direct store
#pragma unroll
    for (int nt = 0; nt < 16; ++nt) {
      float* op = out + (((size_t)(b * 64 + o)) * IH + gy0 + nt) * IW + gx0 + l15;
#pragma unroll
      for (int r = 0; r < 4; ++r) op[(size_t)r * IH * IW] = accY[nt][r];
    }
    return;
  }

  // general path: per-patch circular convolution with kc (correct for any filter)
  float* YS = (float*)smem;  // [32][260]
  for (int half = 0; half < 2; ++half) {
    __syncthreads();
    if ((wave >> 1) == half) {
      int c32 = (wave & 1) * 16 + lg * 4;
#pragma unroll
      for (int nt = 0; nt < 16; ++nt)
#pragma unroll
        for (int r = 0; r < 4; ++r) YS[(c32 + r) * 260 + nt * 16 + l15] = accY[nt][r];
    }
    __syncthreads();
    if (t < 128) {
      int o32 = t >> 2, oo = half * 32 + o32, qd = t & 3;
      const float* kp = ws + oo * 64;
      int py0 = (qd >> 1) * 8, px0 = (qd & 1) * 8;
      const float* row = YS + o32 * 260;
      for (int i = 0; i < 8; ++i)
        for (int j = 0; j < 8; ++j) {
          float acc = 0.f;
          for (int a_ = 0; a_ < 8; ++a_)
            for (int b_ = 0; b_ < 8; ++b_)
              acc += kp[a_ * 8 + b_] *
                     row[(py0 + ((i - a_) & 7)) * 16 + px0 + ((j - b_) & 7)];
          out[(((size_t)(b * 64 + oo)) * IH + gy0 + py0 + i) * IW + gx0 + px0 + j] = acc;
        }
    }
  }
}

extern "C" void kernel_launch(void* const* d_in, const int* in_sizes, int n_in,
                              void* d_out, int out_size, void* d_ws, size_t ws_size,
                              hipStream_t stream) {
  const float* x = (const float*)d_in[0];
  const float* w_in = (const float*)d_in[1];
  const float* b_in = (const float*)d_in[2];
  const float* w_dw = (const float*)d_in[3];
  const float* b_dw = (const float*)d_in[4];
  const float* w_out = (const float*)d_in[5];
  const float* b_out = (const float*)d_in[6];
  const float* fftf = (const float*)d_in[7];
  float* out = (float*)d_out;
  float* ws = (float*)d_ws;

  edffn_prep<<<160, 64, 0, stream>>>(fftf, w_in, w_out, ws);
  dim3 grid(IW / TILE, IH / TILE, 4);
  edffn_main<<<grid, 256, 0, stream>>>(x, b_in, w_dw, b_dw, b_out, ws, out);
}